// Round 5
// baseline (243.798 us; speedup 1.0000x reference)
//
#include <hip/hip_runtime.h>

#define NB 4
#define NC 9                        // classes 1..9 (background ignored)
#define BATCH_ELEMS (160*160*160)   // 4,096,000
#define NVEC (BATCH_ELEMS/4)        // 1,024,000 int4 per batch
#define BPB 500                     // blocks per batch
#define THREADS 256
#define TPB_BATCH (BPB*THREADS)     // 128,000 threads per batch -> 32 elem/thread
#define NBLK (NB*BPB)               // 2000 blocks
#define NPACK 14                    // 27 counters packed as 16-bit pairs

// d_ws layout: u32 cnt[NBLK][NPACK] ; u32 done_flag (zeroed via 4B memset)

__device__ __forceinline__ void proc(int a, int b,
                                     unsigned long long& accP,
                                     unsigned long long& accT,
                                     unsigned long long& accI)
{
    // 6-bit field per class value 0..9; per-thread max 32 < 63: no overflow
    unsigned long long sa = 1ull << (6 * a);
    unsigned long long sb = 1ull << (6 * b);
    accP += sa;
    accT += sb;
    accI += (a == b) ? sa : 0ull;
}

__global__ __launch_bounds__(THREADS, 8) void dice_fused_kernel(
    const int* __restrict__ y_pred,
    const int* __restrict__ y_true,
    unsigned int* __restrict__ cnt,
    unsigned int* __restrict__ done_flag,
    float* __restrict__ out)
{
    const int batch = blockIdx.x / BPB;
    const int bIn   = blockIdx.x % BPB;
    const int4* __restrict__ p = (const int4*)(y_pred + (size_t)batch * BATCH_ELEMS);
    const int4* __restrict__ t = (const int4*)(y_true + (size_t)batch * BATCH_ELEMS);
    const int tid = bIn * THREADS + threadIdx.x;   // 0..127,999

    unsigned long long accP = 0ull, accT = 0ull, accI = 0ull;

    #pragma unroll
    for (int k = 0; k < 8; k += 2) {
        int4 a0 = p[tid + k * TPB_BATCH];
        int4 b0 = t[tid + k * TPB_BATCH];
        int4 a1 = p[tid + (k + 1) * TPB_BATCH];
        int4 b1 = t[tid + (k + 1) * TPB_BATCH];
        proc(a0.x, b0.x, accP, accT, accI);
        proc(a0.y, b0.y, accP, accT, accI);
        proc(a0.z, b0.z, accP, accT, accI);
        proc(a0.w, b0.w, accP, accT, accI);
        proc(a1.x, b1.x, accP, accT, accI);
        proc(a1.y, b1.y, accP, accT, accI);
        proc(a1.z, b1.z, accP, accT, accI);
        proc(a1.w, b1.w, accP, accT, accI);
    }

    // Extract 27 per-thread counts (max 32), packed two per u32 (16-bit halves).
    unsigned int packed[NPACK];
    #pragma unroll
    for (int j = 0; j < NPACK; ++j) {
        int k0 = 2 * j, k1 = 2 * j + 1;
        int c0 = (k0 % 9) + 1, t0 = k0 / 9;
        unsigned long long x0 = (t0 == 0) ? accP : (t0 == 1) ? accT : accI;
        unsigned int v0 = (unsigned int)((x0 >> (6 * c0)) & 63ull);
        unsigned int v1 = 0;
        if (k1 < 27) {
            int c1 = (k1 % 9) + 1, t1 = k1 / 9;
            unsigned long long x1 = (t1 == 0) ? accP : (t1 == 1) ? accT : accI;
            v1 = (unsigned int)((x1 >> (6 * c1)) & 63ull);
        }
        packed[j] = v0 | (v1 << 16);
    }

    // Wave reduction: halves max 32*64 = 2048, no overflow.
    #pragma unroll
    for (int off = 32; off > 0; off >>= 1) {
        #pragma unroll
        for (int j = 0; j < NPACK; ++j)
            packed[j] += __shfl_down(packed[j], off, 64);
    }

    __shared__ unsigned int swave[4][NPACK];
    const int wave = threadIdx.x >> 6;
    const int lane = threadIdx.x & 63;
    if (lane == 0) {
        #pragma unroll
        for (int j = 0; j < NPACK; ++j) swave[wave][j] = packed[j];
    }
    __syncthreads();
    if (threadIdx.x < NPACK) {
        // per-block per-class max 256*32 = 8192: fits 16-bit halves
        unsigned int s = swave[0][threadIdx.x] + swave[1][threadIdx.x]
                       + swave[2][threadIdx.x] + swave[3][threadIdx.x];
        cnt[blockIdx.x * NPACK + threadIdx.x] = s;   // plain store
    }

    // ---- last-block-done: one block survives to reduce all partials ----
    __syncthreads();
    __shared__ bool amLast;
    if (threadIdx.x == 0) {
        __threadfence();                               // publish cnt stores
        amLast = (atomicAdd(done_flag, 1u) == NBLK - 1);
    }
    __syncthreads();
    if (!amLast) return;
    __threadfence();                                   // see all cnt stores

    // 256 threads = 4 waves; wave w reduces batch w's 500 partial rows.
    const int myBatch = wave;
    unsigned int c27[27];
    #pragma unroll
    for (int k = 0; k < 27; ++k) c27[k] = 0u;
    for (int b = lane; b < BPB; b += 64) {
        const unsigned int* row = cnt + (size_t)(myBatch * BPB + b) * NPACK;
        #pragma unroll
        for (int j = 0; j < NPACK; ++j) {
            unsigned int v = row[j];
            c27[2 * j] += v & 0xFFFFu;
            if (2 * j + 1 < 27) c27[2 * j + 1] += v >> 16;
        }
    }
    #pragma unroll
    for (int off = 32; off > 0; off >>= 1) {
        #pragma unroll
        for (int k = 0; k < 27; ++k)
            c27[k] += __shfl_down(c27[k], off, 64);
    }
    __shared__ unsigned int tot[NB * 27];
    if (lane == 0) {
        #pragma unroll
        for (int k = 0; k < 27; ++k) tot[myBatch * 27 + k] = c27[k];
    }
    __syncthreads();

    if (threadIdx.x == 0) {
        float loss = 0.0f;
        for (int n = 0; n < NB; ++n) {
            const unsigned int* c = &tot[n * 27];
            float tsum = 0.0f;
            for (int i = 0; i < NC; ++i) tsum += (float)c[9 + i];
            for (int i = 0; i < NC; ++i) {
                float cp = (float)c[0 + i];
                float ct = (float)c[9 + i];
                float I  = (float)c[18 + i];
                float denom = cp + ct;
                if (denom > 0.0f)
                    loss += (ct / tsum / (float)NB) * (2.0f * I / denom);
            }
        }
        out[0] = 1.0f - loss;
    }
}

extern "C" void kernel_launch(void* const* d_in, const int* in_sizes, int n_in,
                              void* d_out, int out_size, void* d_ws, size_t ws_size,
                              hipStream_t stream) {
    const int* y_pred = (const int*)d_in[0];
    const int* y_true = (const int*)d_in[1];
    unsigned int* cnt  = (unsigned int*)d_ws;          // NBLK*NPACK u32 = 112 KB
    unsigned int* flag = cnt + NBLK * NPACK;           // 1 u32

    hipMemsetAsync(flag, 0, sizeof(unsigned int), stream);
    dice_fused_kernel<<<NBLK, THREADS, 0, stream>>>(y_pred, y_true, cnt, flag,
                                                    (float*)d_out);
}

// Round 6
// 148.921 us; speedup vs baseline: 1.6371x; 1.6371x over previous
//
#include <hip/hip_runtime.h>

#define NB 4
#define NC 9                        // classes 1..9 (background ignored)
#define BATCH_ELEMS (160*160*160)   // 4,096,000
#define NVEC (BATCH_ELEMS/4)        // 1,024,000 int4 per batch
#define BPB 500                     // blocks per batch
#define THREADS 256
#define TPB_BATCH (BPB*THREADS)     // 128,000 threads per batch -> 32 elem/thread
#define NBLK (NB*BPB)               // 2000 blocks
#define NPACK 14                    // 27 counters packed as 16-bit pairs

typedef int v4i __attribute__((ext_vector_type(4)));

// d_ws layout: u32 cnt[NBLK][NPACK]  (per-block partials, plain stores, no memset)

__device__ __forceinline__ void proc(int a, int b,
                                     unsigned long long& accP,
                                     unsigned long long& accT,
                                     unsigned long long& accI)
{
    // 6-bit field per class value 0..9; per-thread max 32 < 63: no overflow
    unsigned long long sa = 1ull << (6 * a);
    unsigned long long sb = 1ull << (6 * b);
    accP += sa;
    accT += sb;
    accI += (a == b) ? sa : 0ull;
}

__global__ __launch_bounds__(THREADS, 8) void dice_hist_kernel(
    const int* __restrict__ y_pred,
    const int* __restrict__ y_true,
    unsigned int* __restrict__ cnt)
{
    const int batch = blockIdx.x / BPB;
    const int bIn   = blockIdx.x % BPB;
    const v4i* __restrict__ p = (const v4i*)(y_pred + (size_t)batch * BATCH_ELEMS);
    const v4i* __restrict__ t = (const v4i*)(y_true + (size_t)batch * BATCH_ELEMS);
    const int tid = bIn * THREADS + threadIdx.x;   // 0..127,999

    unsigned long long accP = 0ull, accT = 0ull, accI = 0ull;

    #pragma unroll
    for (int k = 0; k < 8; k += 2) {
        v4i a0 = __builtin_nontemporal_load(&p[tid + k * TPB_BATCH]);
        v4i b0 = __builtin_nontemporal_load(&t[tid + k * TPB_BATCH]);
        v4i a1 = __builtin_nontemporal_load(&p[tid + (k + 1) * TPB_BATCH]);
        v4i b1 = __builtin_nontemporal_load(&t[tid + (k + 1) * TPB_BATCH]);
        proc(a0.x, b0.x, accP, accT, accI);
        proc(a0.y, b0.y, accP, accT, accI);
        proc(a0.z, b0.z, accP, accT, accI);
        proc(a0.w, b0.w, accP, accT, accI);
        proc(a1.x, b1.x, accP, accT, accI);
        proc(a1.y, b1.y, accP, accT, accI);
        proc(a1.z, b1.z, accP, accT, accI);
        proc(a1.w, b1.w, accP, accT, accI);
    }

    // Extract 27 per-thread counts (max 32), packed two per u32 (16-bit halves).
    unsigned int packed[NPACK];
    #pragma unroll
    for (int j = 0; j < NPACK; ++j) {
        int k0 = 2 * j, k1 = 2 * j + 1;
        int c0 = (k0 % 9) + 1, t0 = k0 / 9;
        unsigned long long x0 = (t0 == 0) ? accP : (t0 == 1) ? accT : accI;
        unsigned int v0 = (unsigned int)((x0 >> (6 * c0)) & 63ull);
        unsigned int v1 = 0;
        if (k1 < 27) {
            int c1 = (k1 % 9) + 1, t1 = k1 / 9;
            unsigned long long x1 = (t1 == 0) ? accP : (t1 == 1) ? accT : accI;
            v1 = (unsigned int)((x1 >> (6 * c1)) & 63ull);
        }
        packed[j] = v0 | (v1 << 16);
    }

    // Wave reduction: halves max 32*64 = 2048, no overflow.
    #pragma unroll
    for (int off = 32; off > 0; off >>= 1) {
        #pragma unroll
        for (int j = 0; j < NPACK; ++j)
            packed[j] += __shfl_down(packed[j], off, 64);
    }

    __shared__ unsigned int swave[4][NPACK];
    const int wave = threadIdx.x >> 6;
    const int lane = threadIdx.x & 63;
    if (lane == 0) {
        #pragma unroll
        for (int j = 0; j < NPACK; ++j) swave[wave][j] = packed[j];
    }
    __syncthreads();
    if (threadIdx.x < NPACK) {
        // per-block per-class max 256*32 = 8192: fits 16-bit halves
        unsigned int s = swave[0][threadIdx.x] + swave[1][threadIdx.x]
                       + swave[2][threadIdx.x] + swave[3][threadIdx.x];
        cnt[blockIdx.x * NPACK + threadIdx.x] = s;   // plain store, no atomic
    }
}

// One block, 1024 threads = 16 waves. Wave w -> batch w/4, quarter q = w&3
// covering 125 of the batch's 500 block-partials. Lane l sums blocks
// q*125+l and q*125+64+l (if l<61) packed (<=16384, safe in 16-bit halves),
// unpacks to 27 u32, shuffle-reduces across the wave, lane 0 does 27 LDS
// atomics. 432 LDS atomics total, then thread 0 computes the loss.
__global__ __launch_bounds__(1024) void dice_finish_kernel(
    const unsigned int* __restrict__ cnt, float* __restrict__ out)
{
    __shared__ unsigned int tot[NB * 27];
    const int tid = threadIdx.x;
    if (tid < NB * 27) tot[tid] = 0u;
    __syncthreads();

    const int w = tid >> 6, l = tid & 63;
    const int batch = w >> 2, q = w & 3;
    const int base = batch * BPB + q * 125;

    unsigned int pk[NPACK];
    const unsigned int* r0 = cnt + (size_t)(base + l) * NPACK;
    #pragma unroll
    for (int j = 0; j < NPACK; ++j) pk[j] = r0[j];
    if (l < 61) {
        const unsigned int* r1 = cnt + (size_t)(base + 64 + l) * NPACK;
        #pragma unroll
        for (int j = 0; j < NPACK; ++j) pk[j] += r1[j];
    }

    unsigned int c27[27];
    #pragma unroll
    for (int j = 0; j < NPACK; ++j) {
        c27[2 * j] = pk[j] & 0xFFFFu;
        if (2 * j + 1 < 27) c27[2 * j + 1] = pk[j] >> 16;
    }

    #pragma unroll
    for (int off = 32; off > 0; off >>= 1) {
        #pragma unroll
        for (int k = 0; k < 27; ++k)
            c27[k] += __shfl_down(c27[k], off, 64);
    }
    if (l == 0) {
        #pragma unroll
        for (int k = 0; k < 27; ++k)
            atomicAdd(&tot[batch * 27 + k], c27[k]);
    }
    __syncthreads();

    if (tid == 0) {
        float loss = 0.0f;
        for (int n = 0; n < NB; ++n) {
            const unsigned int* c = &tot[n * 27];
            float tsum = 0.0f;
            for (int i = 0; i < NC; ++i) tsum += (float)c[9 + i];
            for (int i = 0; i < NC; ++i) {
                float cp = (float)c[0 + i];
                float ct = (float)c[9 + i];
                float I  = (float)c[18 + i];
                float denom = cp + ct;
                if (denom > 0.0f)
                    loss += (ct / tsum / (float)NB) * (2.0f * I / denom);
            }
        }
        out[0] = 1.0f - loss;
    }
}

extern "C" void kernel_launch(void* const* d_in, const int* in_sizes, int n_in,
                              void* d_out, int out_size, void* d_ws, size_t ws_size,
                              hipStream_t stream) {
    const int* y_pred = (const int*)d_in[0];
    const int* y_true = (const int*)d_in[1];
    unsigned int* cnt = (unsigned int*)d_ws;   // NBLK*NPACK u32 = 112 KB, fully overwritten

    dice_hist_kernel<<<NBLK, THREADS, 0, stream>>>(y_pred, y_true, cnt);
    dice_finish_kernel<<<1, 1024, 0, stream>>>(cnt, (float*)d_out);
}